// Round 5
// baseline (298.028 us; speedup 1.0000x reference)
//
#include <hip/hip_runtime.h>
#include <math.h>

#define SIG 512
#define NA 45
#define DD 725          // DIAG
#define PB 106          // PAD_BEFORE
#define HALFF 362.0f    // 0.5*(DD-1); (2/724)*362 == 1 exactly
#define PI_D 3.14159265358979323846

// 32x32 (d x yi) tiles, ONE WAVE (64 thr) per tile; footprint <= 50x47.
// 10.24 KB LDS -> 15 blocks/CU. Proven best shape (44.07us, R2).
#define TD2 32
#define TY2 32
#define NT2 23          // ceil(725/32)
#define NC42 13         // float4 cols staged (52 floats >= 50 needed)
#define RW2 52          // region row stride in floats
#define RH2 47
#define NREG2 640       // 10 chunks x 64 lanes of float4 (>= 47*13=611)
#define NTILES2 (2 * NA * NT2 * NT2)  // 47610
#define TGRP (NT2 * NT2)              // 529 tiles per (b,a) group

// ===== INSTRUMENTATION (this round only) =====
// radon repeats its tile body RPT_R x: rep 0 -> real z, reps >0 -> dummy
// buffer (result bit-identical to baseline). iradon repeats compute+store
// RPT_I x (idempotent stores; asm-laundered zero defeats LICM/DSE).
// Purpose: push per-dispatch dur past the ~39us harness fills so rocprof
// top-5 finally shows OUR kernels' counters. Real per-kernel time =
// row_dur / RPT.
#define RPT_R 8
#define RPT_I 16

// z rows padded: stride 728, cell 0 and 726..727 are zero guards.
#define ZSTR 728
#define ZELEMS (2 * NA * ZSTR)        // 65520
#define TBLOFF ZELEMS                 // 90-float cos/sin table
#define DESCOFF 65616                 // 16B-aligned float index for desc
#define DESCI 12                      // ints per tile descriptor (48B)
#define BMOFF (DESCOFF + NTILES2 * DESCI)      // live-tile bitmap (dwords)
#define BMWORDS 1492                            // ceil(47610/32)=1488 + pad
#define ZDUPOFF (BMOFF + BMWORDS)     // dummy z for instrumentation reps
#define WS_NEED ((ZDUPOFF + ZELEMS) * 4)
#define WS_TBL ((TBLOFF + 2 * NA) * 4)

#define NZB 256                       // prep blocks for z-init
#define NSB 186                       // prep blocks for desc (47610/256)

// iradon tiling
#define SEGW 52

__device__ __forceinline__ float cidx(int i) {
    return -1.0f + (float)i * (2.0f / 724.0f);
}

__device__ __forceinline__ void ref_trig(int a, float& ct, float& st) {
    float thf = (float)((double)(4 * a) * PI_D / 180.0);
    ct = (float)cos((double)thf);
    st = (float)sin((double)thf);
}

// Tile geometry with BOTH-axis integer clipping. Returns false if dead.
// dlohi = (dclo-d0) | (dchi-d0)<<8 ; kske = (yclo-y0) | (ychi-y0)<<8.
__device__ __forceinline__ bool tile_geom(
    int a, int b, int td, int ty, float ct, float st,
    int& dlohi, int& gcb, int& grb, int& nrows, int& kske, int& y0i,
    int& zbase, int& boff, float& pxbase, float& pybase) {
    float X0 = HALFF * (1.0f - ct - st);
    float Y0 = HALFF * (1.0f + st - ct);
    int d0 = td * TD2, dmax = min(d0 + TD2 - 1, DD - 1);
    int y0 = ty * TY2, ymax = min(y0 + TY2 - 1, DD - 1);
    const float lo = (float)(PB - 1), hi = (float)(PB + SIG);

    // ---- yi-interval (over the full d-range of the tile), +-1 margin
    float Ax0 = fmaf(ct, (float)d0, X0), Ax1 = fmaf(ct, (float)dmax, X0);
    float Axlo = fminf(Ax0, Ax1), Axhi = fmaxf(Ax0, Ax1);
    float Ay0 = fmaf(-st, (float)d0, Y0), Ay1 = fmaf(-st, (float)dmax, Y0);
    float Aylo = fminf(Ay0, Ay1), Ayhi = fmaxf(Ay0, Ay1);
    float ylo = (float)y0, yhi = (float)ymax;
    if (st > 1e-6f) {
        ylo = fmaxf(ylo, (lo - Axhi) / st - 1.0f);
        yhi = fminf(yhi, (hi - Axlo) / st + 1.0f);
    } else if (Axhi <= lo || Axlo >= hi) { return false; }
    if (ct > 1e-6f) {
        ylo = fmaxf(ylo, (lo - Ayhi) / ct - 1.0f);
        yhi = fminf(yhi, (hi - Aylo) / ct + 1.0f);
    } else if (ct < -1e-6f) {
        ylo = fmaxf(ylo, (hi - Aylo) / ct - 1.0f);
        yhi = fminf(yhi, (lo - Ayhi) / ct + 1.0f);
    } else if (Ayhi <= lo || Aylo >= hi) { return false; }
    int yclo = max(y0, (int)ceilf(ylo));
    int ychi = min(ymax, (int)floorf(yhi));
    if (ychi < yclo) return false;
    float yclof = (float)yclo, ychif = (float)ychi;

    // ---- d-interval given yi in [yclo,ychi], +-1 margin
    float dloF = (float)d0, dhiF = (float)dmax;
    if (ct > 1e-6f) {
        dloF = fmaxf(dloF, (lo - st * ychif - X0) / ct - 1.0f);
        dhiF = fminf(dhiF, (hi - st * yclof - X0) / ct + 1.0f);
    } else if (ct < -1e-6f) {
        dloF = fmaxf(dloF, (hi - st * yclof - X0) / ct - 1.0f);
        dhiF = fminf(dhiF, (lo - st * ychif - X0) / ct + 1.0f);
    }   // |ct| tiny: px independent of d (yi-solve covered px)
    if (st > 1e-6f) {
        float yl2 = (ct >= 0.0f) ? yclof : ychif;
        float yh2 = (ct >= 0.0f) ? ychif : yclof;
        dloF = fmaxf(dloF, (Y0 + ct * yl2 - hi) / st - 1.0f);
        dhiF = fminf(dhiF, (Y0 + ct * yh2 - lo) / st + 1.0f);
    }   // st tiny: py independent of d (yi-solve covered py)
    int dclo = max(d0, (int)ceilf(dloF));
    int dchi = min(dmax, (int)floorf(dhiF));
    if (dchi < dclo) return false;

    // ---- bbox from the CLIPPED rect corners (tight rows/cols)
    float pxmin = 1e30f, pxmax = -1e30f, pymin = 1e30f, pymax = -1e30f;
    for (int ci = 0; ci < 4; ++ci) {
        float df = (float)((ci & 1) ? dchi : dclo);
        float yf = (float)((ci & 2) ? ychi : yclo);
        float px = fmaf(st, yf, fmaf(ct, df, X0));
        float py = fmaf(ct, yf, fmaf(-st, df, Y0));
        pxmin = fminf(pxmin, px); pxmax = fmaxf(pxmax, px);
        pymin = fminf(pymin, py); pymax = fmaxf(pymax, py);
    }
    int cx0 = (int)floorf(pxmin) - 1;
    int cx1 = (int)floorf(pxmax) + 2;
    int ry0 = (int)floorf(pymin) - 1;
    int ry1 = (int)floorf(pymax) + 2;
    if (cx1 < PB || cx0 >= PB + SIG || ry1 < PB || ry0 >= PB + SIG) return false;

    int cx0a = PB + (((cx0 - PB) >> 2) << 2);   // 4-col aligned
    nrows = min(ry1 - ry0 + 1, RH2);
    gcb = cx0a - PB;
    grb = ry0 - PB;
    dlohi = (dclo - d0) | ((dchi - d0) << 8);
    kske = (yclo - y0) | ((ychi - y0) << 8);
    y0i = y0;
    zbase = (b * NA + a) * ZSTR + 1 + d0;
    boff = b * SIG * SIG;
    pxbase = fmaf(ct, (float)d0, X0) - (float)cx0a;
    pybase = fmaf(-st, (float)d0, Y0) - (float)ry0;
    return true;
}

// Kernel 0 (fused prep): blocks [0,NZB) init z rows (+trig tbl, zpage in
// block 0); blocks [NZB,NZB+NSB) build tile descriptors + live bitmap.
template <int MODE>   // 2 = z+tbl+desc+bitmap, 1 = z+tbl, 0 = z only
__global__ void prep(const float* __restrict__ yin, float* __restrict__ z,
                     float* __restrict__ tbl, float* __restrict__ zpage,
                     int* __restrict__ desc, unsigned* __restrict__ bmap) {
    __shared__ float s_trig[4];
    __shared__ int s_ag[2];
    if (blockIdx.x < NZB) {
        int i = blockIdx.x * blockDim.x + threadIdx.x;
        if (i < 256) zpage[i] = 0.0f;
        if (MODE >= 1 && blockIdx.x == 0 && threadIdx.x < NA) {
            float ct, st;
            ref_trig(threadIdx.x, ct, st);
            tbl[2 * threadIdx.x] = ct;
            tbl[2 * threadIdx.x + 1] = st;
        }
        if (i >= ZELEMS) return;
        int r = i / ZSTR;                 // (b*NA + a)
        int c = i - r * ZSTR;
        float v = 0.0f;
        if (c >= 1 && c <= DD) {
            int d = c - 1;
            int a = r % NA;
            int b = r / NA;
            v = -yin[(b * DD + d) * NA + a];
        }
        z[i] = v;
        return;
    }
    if (MODE < 2) return;
    int base = (blockIdx.x - NZB) * blockDim.x;
    if (threadIdx.x < 2) {
        int tl = min(base + (int)threadIdx.x * 255, NTILES2 - 1);
        int ag = tl / TGRP;               // b*NA + a
        s_ag[threadIdx.x] = ag;
        float ct, st;
        ref_trig(ag % NA, ct, st);
        s_trig[2 * threadIdx.x] = ct;
        s_trig[2 * threadIdx.x + 1] = st;
    }
    __syncthreads();
    int tile = base + threadIdx.x;
    bool live = false;
    int dlohi, gcb, grb, nrows, kske, y0i, zbase, boff;
    float pxbase, pybase;
    float ct = 0.0f, st = 0.0f;
    if (tile < NTILES2) {
        int td = tile % NT2; int rest = tile / NT2;
        int ty = rest % NT2;
        int ag = rest / NT2;              // b*NA + a
        int a = ag % NA;
        int b = ag / NA;
        int sel = (ag == s_ag[0]) ? 0 : 2;
        ct = s_trig[sel]; st = s_trig[sel + 1];
        live = tile_geom(a, b, td, ty, ct, st, dlohi, gcb, grb, nrows, kske,
                         y0i, zbase, boff, pxbase, pybase);
    }
    unsigned long long m = __ballot(live);
    if ((threadIdx.x & 63) == 0) {        // lane0 tile is 64-aligned
        int w = tile >> 5;
        bmap[w] = (unsigned)m;
        bmap[w + 1] = (unsigned)(m >> 32);
    }
    if (!live) return;
    int* dp = desc + tile * DESCI;
    float* fp = (float*)dp;
    dp[0] = dlohi; dp[1] = gcb; dp[2] = grb; dp[3] = nrows;
    dp[4] = kske; fp[5] = pxbase; fp[6] = pybase;
    dp[7] = y0i; dp[8] = zbase; dp[9] = boff;
    fp[10] = ct; fp[11] = st;             // trig embedded: no tbl load in radon
}

// One-wave tile body: async-stage clipped footprint, sample, shfl-reduce,
// masked atomicAdd (lanes outside the live d-range clamp & discard).
__device__ __forceinline__ void process_tile32(
    const float* __restrict__ img, const float* __restrict__ zpage,
    float ct, float st,
    int dlohi, int gcb, int grb, int nrows, int kske, int y0i, int zbase,
    float pxbase, float pybase,
    float4* reg4, float* __restrict__ z) {
    float* reg = (float*)reg4;
    int lane = threadIdx.x;                      // 0..63

    // Stage: contiguous float4 stream via 16B global_load_lds (linear LDS
    // dest = wave base + lane*16; per-lane global src; OOB lanes -> zpage).
    int nch = (nrows * NC42 + 63) >> 6;          // <= 10
    for (int ch = 0; ch < nch; ++ch) {
        int vi = (ch << 6) + lane;
        int r = vi / NC42;                       // compile-time magic div
        int c = vi - r * NC42;
        int gr = grb + r;
        int gc = gcb + (c << 2);                 // multiple of 4
        bool valid = ((unsigned)gr < SIG) & ((unsigned)gc < SIG);
        const float* src = valid ? (img + (gr << 9) + gc) : zpage;
        __builtin_amdgcn_global_load_lds(
            (const __attribute__((address_space(1))) void*)src,
            (__attribute__((address_space(3))) void*)(reg4 + (ch << 6)),
            16, 0, 0);
    }
    __syncthreads();                             // 1 wave: vmcnt fence

    // Sample: lanes = 32 d-values x 2 yi-halves; clipped yi-span split
    // across halves (uniform per tile -> no divergence).
    int half = lane >> 5;
    int dl = lane & 31;
    int ksb = kske & 255, keb = kske >> 8;       // keb >= ksb guaranteed
    int dlo = dlohi & 255, dhi = dlohi >> 8;
    int n = keb - ksb + 1;
    int sq = ksb + ((n * half) >> 1);
    int eq = ksb + ((n * (half + 1)) >> 1) - 1;

    float lf = (float)min(max(dl, dlo), dhi);    // clamp into live d-range
    float pxd = fmaf(ct, lf, pxbase);
    float pyd = fmaf(-st, lf, pybase);
    float sum = 0.0f;
    float yif = (float)(y0i + sq);
#pragma unroll 4
    for (int k = sq; k <= eq; ++k) {
        float px = fmaf(st, yif, pxd);
        float py = fmaf(ct, yif, pyd);
        float fx = floorf(px), fy = floorf(py);
        float wx = px - fx, wy = py - fy;
        int addr = (int)fmaf(fy, (float)RW2, fx);    // exact: < 2^24
        float v00 = reg[addr],       v10 = reg[addr + 1];
        float v01 = reg[addr + RW2], v11 = reg[addr + RW2 + 1];
        float top = fmaf(wx, v10 - v00, v00);
        float bot = fmaf(wx, v11 - v01, v01);
        sum = fmaf(wy, bot - top, sum + top);
        yif += 1.0f;
    }
    sum += __shfl_xor(sum, 32);                  // pair (dl, dl+32)
    if (half == 0 && dl >= dlo && dl <= dhi) {   // only live d-lanes emit
        atomicAdd(&z[zbase + dl], sum);
    }
}

// Kernel 1 (instrumented): one wave per tile; body repeated RPT_R x.
// Rep 0 accumulates into the REAL z; reps >0 into zdup (never read) —
// final result bit-identical to the 44.07us baseline, duration ~RPT_R x
// so rocprof surfaces this kernel's counters above the harness fills.
template <int RPT>
__global__ __launch_bounds__(64) void radon32p(const float* __restrict__ x,
                                               const float* __restrict__ zpage,
                                               const int* __restrict__ desc,
                                               const unsigned* __restrict__ bmap,
                                               float* __restrict__ z,
                                               float* __restrict__ zdup) {
    __shared__ float4 reg4[NREG2];
    unsigned w = bmap[blockIdx.x >> 5];          // uniform -> s_load, K$-hot
    if (!((w >> (blockIdx.x & 31)) & 1u)) return;
    const int* dp = desc + blockIdx.x * DESCI;
    const float* fp = (const float*)dp;
#pragma unroll 1
    for (int rep = 0; rep < RPT; ++rep) {
        if (rep) __syncthreads();                // LDS reuse fence between reps
        process_tile32(x + dp[9], zpage, fp[10], fp[11],
                       dp[0], dp[1], dp[2], dp[3], dp[4], dp[7], dp[8],
                       fp[5], fp[6], reg4, rep == 0 ? z : zdup);
    }
}

// Fallback kernel 1: one 64-thread block per tile, geometry inline.
template <int TBL>
__global__ __launch_bounds__(64) void radon32(const float* __restrict__ x,
                                              const float* __restrict__ zpage,
                                              const float* __restrict__ tbl,
                                              float* __restrict__ z) {
    __shared__ float4 reg4[NREG2];
    int tile = blockIdx.x;
    int td = tile % NT2; int rest = tile / NT2;
    int ty = rest % NT2; rest /= NT2;
    int a = rest % NA;
    int b = rest / NA;
    float ct, st;
    if (TBL) { ct = tbl[2 * a]; st = tbl[2 * a + 1]; }
    else     { ref_trig(a, ct, st); }
    int dlohi, gcb, grb, nrows, kske, y0i, zbase, boff;
    float pxbase, pybase;
    if (!tile_geom(a, b, td, ty, ct, st, dlohi, gcb, grb, nrows, kske, y0i,
                   zbase, boff, pxbase, pybase)) return;
    process_tile32(x + boff, zpage, ct, st, dlohi, gcb, grb, nrows, kske,
                   y0i, zbase, pxbase, pybase, reg4, z);
}

// Kernel 2 (instrumented): tiled backprojection, compute+store repeated
// RPT_I x with identical results (stores idempotent). z0 is an asm-
// laundered zero folded into LDS/store addressing so LICM/DSE cannot
// hoist the compute or drop the stores (rule #17).
template <int TBL, int RPT>
__global__ __launch_bounds__(256) void iradon_t(const float* __restrict__ z,
                                                const float* __restrict__ tbl,
                                                float* __restrict__ out) {
    __shared__ float s_sc[NA], s_st2[NA];
    __shared__ int s_lo[NA];
    __shared__ float s_B[NA * 32];
    __shared__ float s_seg[NA * SEGW];

    int t = threadIdx.x;
    int b = blockIdx.x >> 8;
    int tb = blockIdx.x & 255;
    int i0 = (tb >> 4) << 5;
    int j0 = (tb & 15) << 5;

    if (t < NA) {
        float ct, st;
        if (TBL) { ct = tbl[2 * t]; st = tbl[2 * t + 1]; }
        else     { ref_trig(t, ct, st); }
        float sc = ct * HALFF;
        float st2 = -st * HALFF;
        float cxl = cidx(j0 + PB), cxh = cidx(j0 + 31 + PB);
        float cyl = cidx(i0 + PB), cyh = cidx(i0 + 31 + PB);
        float a00 = fmaf(sc, cxl, fmaf(st2, cyl, 363.0f));
        float a01 = fmaf(sc, cxl, fmaf(st2, cyh, 363.0f));
        float a10 = fmaf(sc, cxh, fmaf(st2, cyl, 363.0f));
        float a11 = fmaf(sc, cxh, fmaf(st2, cyh, 363.0f));
        float mn = fminf(fminf(a00, a01), fminf(a10, a11));
        int lo = (int)floorf(mn) - 1;
        lo = min(max(lo, 0), ZSTR - 1 - SEGW);   // keep lo..lo+51 in-row
        s_sc[t] = sc; s_st2[t] = st2; s_lo[t] = lo;
    }
    __syncthreads();

    // Row-base table: B[a][ii] = st2*cy(i0+ii) + (363 - lo)
    for (int s = t; s < NA * 32; s += 256) {
        int a = s >> 5, ii = s & 31;
        s_B[s] = fmaf(s_st2[a], cidx(i0 + ii + PB), 363.0f - (float)s_lo[a]);
    }
    // Stage z segments (L2 -> LDS, coalesced runs of 52)
    const float* zb = z + b * NA * ZSTR;
    for (int s = t; s < NA * SEGW; s += 256) {
        unsigned a = (unsigned)s / SEGW;
        int idx = s - (int)(a * SEGW);
        s_seg[s] = zb[a * ZSTR + s_lo[a] + idx];
    }
    __syncthreads();

    float cxv = cidx(j0 + (t & 31) + PB);
    int r0 = t >> 5;                              // 0..7
    const float sfin = (float)(PI_D / (2.0 * NA));
    int j = j0 + (t & 31);
    int ob = (b << 18) + j;

#pragma unroll 1
    for (int rep = 0; rep < RPT; ++rep) {
        int z0 = 0;
        asm volatile("" : "+v"(z0));              // opaque zero per rep
        float acc0 = 0.f, acc1 = 0.f, acc2 = 0.f, acc3 = 0.f;
        for (int a = 0; a < NA; ++a) {
            float sc = s_sc[a];
            const float* B = s_B + (a << 5) + r0 + z0;
            const float* seg = s_seg + a * SEGW + z0;
#define IR_TAP(ACC, OFF)                                                     \
            {   float af = fmaf(sc, cxv, B[OFF]);                            \
                float fl = floorf(af);                                       \
                float wt = af - fl;                                          \
                int ia = min(max((int)af, 0), SEGW - 2);                     \
                float v0 = seg[ia], v1 = seg[ia + 1];                        \
                ACC = fmaf(wt, v1 - v0, ACC + v0); }
            IR_TAP(acc0, 0)
            IR_TAP(acc1, 8)
            IR_TAP(acc2, 16)
            IR_TAP(acc3, 24)
#undef IR_TAP
        }
        out[ob + ((i0 + r0) << 9) + z0]      = acc0 * sfin;
        out[ob + ((i0 + r0 + 8) << 9) + z0]  = acc1 * sfin;
        out[ob + ((i0 + r0 + 16) << 9) + z0] = acc2 * sfin;
        out[ob + ((i0 + r0 + 24) << 9) + z0] = acc3 * sfin;
    }
}

extern "C" void kernel_launch(void* const* d_in, const int* in_sizes, int n_in,
                              void* d_out, int out_size, void* d_ws, size_t ws_size,
                              hipStream_t stream) {
    const float* x = (const float*)d_in[0];     // (2,1,512,512)
    const float* yin = (const float*)d_in[1];   // (2,1,725,45)
    float* out = (float*)d_out;                 // (2,1,512,512)
    float* z = (float*)d_ws;                    // guard-padded (2,45,728)
    float* tbl = z + TBLOFF;
    int* desc = (int*)(z + DESCOFF);
    unsigned* bmap = (unsigned*)(z + BMOFF);
    float* zdup = z + ZDUPOFF;                  // dummy atomic sink (reps>0)
    float* zpage = out;                         // 256 zeros; iradon overwrites

    if (ws_size >= (size_t)WS_NEED) {
        prep<2><<<NZB + NSB, 256, 0, stream>>>(yin, z, tbl, zpage, desc, bmap);
        radon32p<RPT_R><<<NTILES2, 64, 0, stream>>>(x, zpage, desc, bmap, z, zdup);
        iradon_t<1, RPT_I><<<512, 256, 0, stream>>>(z, tbl, out);
    } else if (ws_size >= (size_t)WS_TBL) {
        prep<1><<<NZB, 256, 0, stream>>>(yin, z, tbl, zpage, nullptr, nullptr);
        radon32<1><<<NTILES2, 64, 0, stream>>>(x, zpage, tbl, z);
        iradon_t<1, 1><<<512, 256, 0, stream>>>(z, tbl, out);
    } else {
        prep<0><<<NZB, 256, 0, stream>>>(yin, z, nullptr, zpage, nullptr, nullptr);
        radon32<0><<<NTILES2, 64, 0, stream>>>(x, zpage, nullptr, z);
        iradon_t<0, 1><<<512, 256, 0, stream>>>(z, nullptr, out);
    }
}

// Round 6
// 40.431 us; speedup vs baseline: 7.3713x; 7.3713x over previous
//
#include <hip/hip_runtime.h>
#include <math.h>

#define SIG 512
#define NA 45
#define DD 725          // DIAG
#define PB 106          // PAD_BEFORE
#define HALFF 362.0f    // 0.5*(DD-1); (2/724)*362 == 1 exactly
#define PI_D 3.14159265358979323846

// 32x32 (d x yi) tiles, ONE WAVE (64 thr) per tile; footprint <= 50x47.
// 10.24 KB LDS -> 15 blocks/CU. VALU-bound (R5: VALUBusy ~101%), so this
// round cuts instructions: interior-tile incremental staging + masked-lane
// inner loop. Occupancy/dispatch levers proven dead (R1-R4).
#define TD2 32
#define TY2 32
#define NT2 23          // ceil(725/32)
#define NC42 13         // float4 cols staged (52 floats >= 50 needed)
#define RW2 52          // region row stride in floats
#define RH2 47
#define NREG2 640       // 10 chunks x 64 lanes of float4 (>= 47*13=611)
#define NTILES2 (2 * NA * NT2 * NT2)  // 47610
#define TGRP (NT2 * NT2)              // 529 tiles per (b,a) group

// z rows padded: stride 728, cell 0 and 726..727 are zero guards.
#define ZSTR 728
#define ZELEMS (2 * NA * ZSTR)        // 65520
#define TBLOFF ZELEMS                 // 90-float cos/sin table
#define DESCOFF 65616                 // 16B-aligned float index for desc
#define DESCI 12                      // ints per tile descriptor (48B)
#define BMOFF (DESCOFF + NTILES2 * DESCI)      // live-tile bitmap (dwords)
#define BMWORDS 1492                            // ceil(47610/32)=1488 + pad
#define WS_NEED ((BMOFF + BMWORDS) * 4)
#define WS_TBL ((TBLOFF + 2 * NA) * 4)

#define NZB 256                       // prep blocks for z-init
#define NSB 186                       // prep blocks for desc (47610/256)

// iradon: 16x16 px tiles -> 2048 blocks (8/CU, 32 waves/CU; was 512=2/CU,
// latency-starved at 7us vs ~2.5us compute — R5 decomposition).
#define SEGW2 32

__device__ __forceinline__ float cidx(int i) {
    return -1.0f + (float)i * (2.0f / 724.0f);
}

__device__ __forceinline__ void ref_trig(int a, float& ct, float& st) {
    float thf = (float)((double)(4 * a) * PI_D / 180.0);
    ct = (float)cos((double)thf);
    st = (float)sin((double)thf);
}

// Tile geometry with BOTH-axis integer clipping. Returns false if dead.
// dlohi = (dclo-d0) | (dchi-d0)<<8 ; kske = (yclo-y0) | (ychi-y0)<<8.
__device__ __forceinline__ bool tile_geom(
    int a, int b, int td, int ty, float ct, float st,
    int& dlohi, int& gcb, int& grb, int& nrows, int& kske, int& y0i,
    int& zbase, int& boff, float& pxbase, float& pybase) {
    float X0 = HALFF * (1.0f - ct - st);
    float Y0 = HALFF * (1.0f + st - ct);
    int d0 = td * TD2, dmax = min(d0 + TD2 - 1, DD - 1);
    int y0 = ty * TY2, ymax = min(y0 + TY2 - 1, DD - 1);
    const float lo = (float)(PB - 1), hi = (float)(PB + SIG);

    // ---- yi-interval (over the full d-range of the tile), +-1 margin
    float Ax0 = fmaf(ct, (float)d0, X0), Ax1 = fmaf(ct, (float)dmax, X0);
    float Axlo = fminf(Ax0, Ax1), Axhi = fmaxf(Ax0, Ax1);
    float Ay0 = fmaf(-st, (float)d0, Y0), Ay1 = fmaf(-st, (float)dmax, Y0);
    float Aylo = fminf(Ay0, Ay1), Ayhi = fmaxf(Ay0, Ay1);
    float ylo = (float)y0, yhi = (float)ymax;
    if (st > 1e-6f) {
        ylo = fmaxf(ylo, (lo - Axhi) / st - 1.0f);
        yhi = fminf(yhi, (hi - Axlo) / st + 1.0f);
    } else if (Axhi <= lo || Axlo >= hi) { return false; }
    if (ct > 1e-6f) {
        ylo = fmaxf(ylo, (lo - Ayhi) / ct - 1.0f);
        yhi = fminf(yhi, (hi - Aylo) / ct + 1.0f);
    } else if (ct < -1e-6f) {
        ylo = fmaxf(ylo, (hi - Aylo) / ct - 1.0f);
        yhi = fminf(yhi, (lo - Ayhi) / ct + 1.0f);
    } else if (Ayhi <= lo || Aylo >= hi) { return false; }
    int yclo = max(y0, (int)ceilf(ylo));
    int ychi = min(ymax, (int)floorf(yhi));
    if (ychi < yclo) return false;
    float yclof = (float)yclo, ychif = (float)ychi;

    // ---- d-interval given yi in [yclo,ychi], +-1 margin
    float dloF = (float)d0, dhiF = (float)dmax;
    if (ct > 1e-6f) {
        dloF = fmaxf(dloF, (lo - st * ychif - X0) / ct - 1.0f);
        dhiF = fminf(dhiF, (hi - st * yclof - X0) / ct + 1.0f);
    } else if (ct < -1e-6f) {
        dloF = fmaxf(dloF, (hi - st * yclof - X0) / ct - 1.0f);
        dhiF = fminf(dhiF, (lo - st * ychif - X0) / ct + 1.0f);
    }   // |ct| tiny: px independent of d (yi-solve covered px)
    if (st > 1e-6f) {
        float yl2 = (ct >= 0.0f) ? yclof : ychif;
        float yh2 = (ct >= 0.0f) ? ychif : yclof;
        dloF = fmaxf(dloF, (Y0 + ct * yl2 - hi) / st - 1.0f);
        dhiF = fminf(dhiF, (Y0 + ct * yh2 - lo) / st + 1.0f);
    }   // st tiny: py independent of d (yi-solve covered py)
    int dclo = max(d0, (int)ceilf(dloF));
    int dchi = min(dmax, (int)floorf(dhiF));
    if (dchi < dclo) return false;

    // ---- bbox from the CLIPPED rect corners (tight rows/cols)
    float pxmin = 1e30f, pxmax = -1e30f, pymin = 1e30f, pymax = -1e30f;
    for (int ci = 0; ci < 4; ++ci) {
        float df = (float)((ci & 1) ? dchi : dclo);
        float yf = (float)((ci & 2) ? ychi : yclo);
        float px = fmaf(st, yf, fmaf(ct, df, X0));
        float py = fmaf(ct, yf, fmaf(-st, df, Y0));
        pxmin = fminf(pxmin, px); pxmax = fmaxf(pxmax, px);
        pymin = fminf(pymin, py); pymax = fmaxf(pymax, py);
    }
    int cx0 = (int)floorf(pxmin) - 1;
    int cx1 = (int)floorf(pxmax) + 2;
    int ry0 = (int)floorf(pymin) - 1;
    int ry1 = (int)floorf(pymax) + 2;
    if (cx1 < PB || cx0 >= PB + SIG || ry1 < PB || ry0 >= PB + SIG) return false;

    int cx0a = PB + (((cx0 - PB) >> 2) << 2);   // 4-col aligned
    nrows = min(ry1 - ry0 + 1, RH2);
    gcb = cx0a - PB;
    grb = ry0 - PB;
    dlohi = (dclo - d0) | ((dchi - d0) << 8);
    kske = (yclo - y0) | ((ychi - y0) << 8);
    y0i = y0;
    zbase = (b * NA + a) * ZSTR + 1 + d0;
    boff = b * SIG * SIG;
    pxbase = fmaf(ct, (float)d0, X0) - (float)cx0a;
    pybase = fmaf(-st, (float)d0, Y0) - (float)ry0;
    return true;
}

// Kernel 0 (fused prep): blocks [0,NZB) init z rows (+trig tbl, zpage in
// block 0); blocks [NZB,NZB+NSB) build tile descriptors + live bitmap.
// Interior flag (whole staged footprint in-image) packed into dlohi bit 16
// -> radon takes the cheap incremental staging path (~75-80% of live tiles).
template <int MODE>   // 2 = z+tbl+desc+bitmap, 1 = z+tbl, 0 = z only
__global__ void prep(const float* __restrict__ yin, float* __restrict__ z,
                     float* __restrict__ tbl, float* __restrict__ zpage,
                     int* __restrict__ desc, unsigned* __restrict__ bmap) {
    __shared__ float s_trig[4];
    __shared__ int s_ag[2];
    if (blockIdx.x < NZB) {
        int i = blockIdx.x * blockDim.x + threadIdx.x;
        if (i < 256) zpage[i] = 0.0f;
        if (MODE >= 1 && blockIdx.x == 0 && threadIdx.x < NA) {
            float ct, st;
            ref_trig(threadIdx.x, ct, st);
            tbl[2 * threadIdx.x] = ct;
            tbl[2 * threadIdx.x + 1] = st;
        }
        if (i >= ZELEMS) return;
        int r = i / ZSTR;                 // (b*NA + a)
        int c = i - r * ZSTR;
        float v = 0.0f;
        if (c >= 1 && c <= DD) {
            int d = c - 1;
            int a = r % NA;
            int b = r / NA;
            v = -yin[(b * DD + d) * NA + a];
        }
        z[i] = v;
        return;
    }
    if (MODE < 2) return;
    int base = (blockIdx.x - NZB) * blockDim.x;
    if (threadIdx.x < 2) {
        int tl = min(base + (int)threadIdx.x * 255, NTILES2 - 1);
        int ag = tl / TGRP;               // b*NA + a
        s_ag[threadIdx.x] = ag;
        float ct, st;
        ref_trig(ag % NA, ct, st);
        s_trig[2 * threadIdx.x] = ct;
        s_trig[2 * threadIdx.x + 1] = st;
    }
    __syncthreads();
    int tile = base + threadIdx.x;
    bool live = false;
    int dlohi, gcb, grb, nrows, kske, y0i, zbase, boff;
    float pxbase, pybase;
    float ct = 0.0f, st = 0.0f;
    if (tile < NTILES2) {
        int td = tile % NT2; int rest = tile / NT2;
        int ty = rest % NT2;
        int ag = rest / NT2;              // b*NA + a
        int a = ag % NA;
        int b = ag / NA;
        int sel = (ag == s_ag[0]) ? 0 : 2;
        ct = s_trig[sel]; st = s_trig[sel + 1];
        live = tile_geom(a, b, td, ty, ct, st, dlohi, gcb, grb, nrows, kske,
                         y0i, zbase, boff, pxbase, pybase);
    }
    unsigned long long m = __ballot(live);
    if ((threadIdx.x & 63) == 0) {        // lane0 tile is 64-aligned
        int w = tile >> 5;
        bmap[w] = (unsigned)m;
        bmap[w + 1] = (unsigned)(m >> 32);
    }
    if (!live) return;
    // interior flag: every staged (r,c) in-image incl. the r-overshoot of
    // the last chunk (rmax = (nch*64-1)/13) and the 16B col reach (+51).
    {
        int nch = (nrows * NC42 + 63) >> 6;
        int rmax = (nch * 64 - 1) / NC42;
        if (grb >= 0 && grb + rmax < SIG && gcb >= 0 && gcb + 52 <= SIG)
            dlohi |= (1 << 16);
    }
    int* dp = desc + tile * DESCI;
    float* fp = (float*)dp;
    dp[0] = dlohi; dp[1] = gcb; dp[2] = grb; dp[3] = nrows;
    dp[4] = kske; fp[5] = pxbase; fp[6] = pybase;
    dp[7] = y0i; dp[8] = zbase; dp[9] = boff;
    fp[10] = ct; fp[11] = st;             // trig embedded: no tbl load in radon
}

// One-wave tile body. Staging: interior tiles walk a 2-case incremental
// 64-bit src pointer (no div/mod/bounds/select per chunk); border tiles use
// the full clamped path. Sample: incremental px/py (add vs fma+counter).
__device__ __forceinline__ void process_tile32(
    const float* __restrict__ img, const float* __restrict__ zpage,
    float ct, float st,
    int dlohi, int gcb, int grb, int nrows, int kske, int y0i, int zbase,
    float pxbase, float pybase,
    float4* reg4, float* __restrict__ z) {
    float* reg = (float*)reg4;
    int lane = threadIdx.x;                      // 0..63

    int nch = (nrows * NC42 + 63) >> 6;          // <= 10
    if (dlohi & (1 << 16)) {
        // Interior fast path. Lane (r,c) walks: vi += 64 => r += 4+carry,
        // c -= 1 (wrap to 12), carry = (c != 0). Two float deltas:
        // carry: 5*512-4 = 2556 ; no-carry: 4*512+48 = 2096.
        int r0 = (lane * 5) >> 6;                // == lane/13 for 0..63
        int c0 = lane - r0 * NC42;
        const float* src = img + ((grb + r0) << 9) + gcb + (c0 << 2);
        for (int ch = 0; ch < nch; ++ch) {
            __builtin_amdgcn_global_load_lds(
                (const __attribute__((address_space(1))) void*)src,
                (__attribute__((address_space(3))) void*)(reg4 + (ch << 6)),
                16, 0, 0);
            bool cy = (c0 != 0);
            src += cy ? (5 * SIG - 4) : (4 * SIG + 48);
            c0 = cy ? (c0 - 1) : (NC42 - 1);
        }
    } else {
        for (int ch = 0; ch < nch; ++ch) {
            int vi = (ch << 6) + lane;
            int r = vi / NC42;                   // compile-time magic div
            int c = vi - r * NC42;
            int gr = grb + r;
            int gc = gcb + (c << 2);             // multiple of 4
            bool valid = ((unsigned)gr < SIG) & ((unsigned)gc < SIG);
            const float* src = valid ? (img + (gr << 9) + gc) : zpage;
            __builtin_amdgcn_global_load_lds(
                (const __attribute__((address_space(1))) void*)src,
                (__attribute__((address_space(3))) void*)(reg4 + (ch << 6)),
                16, 0, 0);
        }
    }
    __syncthreads();                             // 1 wave: vmcnt fence

    // Sample: lanes = 32 d-values x 2 yi-halves; clipped yi-span split
    // across halves (uniform per tile -> no divergence).
    int half = lane >> 5;
    int dl = lane & 31;
    int ksb = kske & 255, keb = kske >> 8;       // keb >= ksb guaranteed
    int dlo = dlohi & 255, dhi = (dlohi >> 8) & 255;
    int n = keb - ksb + 1;
    int sq = ksb + ((n * half) >> 1);
    int eq = ksb + ((n * (half + 1)) >> 1) - 1;

    float lf = (float)min(max(dl, dlo), dhi);    // clamp into live d-range
    float pxd = fmaf(ct, lf, pxbase);
    float pyd = fmaf(-st, lf, pybase);
    float yif = (float)(y0i + sq);
    float px = fmaf(st, yif, pxd);
    float py = fmaf(ct, yif, pyd);
    float sum = 0.0f;
#pragma unroll 4
    for (int k = sq; k <= eq; ++k) {
        float fx = floorf(px), fy = floorf(py);
        float wx = px - fx, wy = py - fy;
        int addr = (int)fmaf(fy, (float)RW2, fx);    // exact: < 2^24
        float v00 = reg[addr],       v10 = reg[addr + 1];
        float v01 = reg[addr + RW2], v11 = reg[addr + RW2 + 1];
        float top = fmaf(wx, v10 - v00, v00);
        float bot = fmaf(wx, v11 - v01, v01);
        sum = fmaf(wy, bot - top, sum + top);
        px += st; py += ct;                      // drift <= 16 ulp(50): ok
    }
    sum += __shfl_xor(sum, 32);                  // pair (dl, dl+32)
    if (half == 0 && dl >= dlo && dl <= dhi) {   // only live d-lanes emit
        atomicAdd(&z[zbase + dl], sum);
    }
}

// Kernel 1: radon, one wave per tile; scalar bitmap gate for dead tiles.
__global__ __launch_bounds__(64) void radon32f(const float* __restrict__ x,
                                               const float* __restrict__ zpage,
                                               const int* __restrict__ desc,
                                               const unsigned* __restrict__ bmap,
                                               float* __restrict__ z) {
    __shared__ float4 reg4[NREG2];
    unsigned w = bmap[blockIdx.x >> 5];          // uniform -> s_load, K$-hot
    if (!((w >> (blockIdx.x & 31)) & 1u)) return;
    const int* dp = desc + blockIdx.x * DESCI;
    const float* fp = (const float*)dp;
    process_tile32(x + dp[9], zpage, fp[10], fp[11],
                   dp[0], dp[1], dp[2], dp[3], dp[4], dp[7], dp[8],
                   fp[5], fp[6], reg4, z);
}

// Fallback kernel 1: one 64-thread block per tile, geometry inline.
template <int TBL>
__global__ __launch_bounds__(64) void radon32(const float* __restrict__ x,
                                              const float* __restrict__ zpage,
                                              const float* __restrict__ tbl,
                                              float* __restrict__ z) {
    __shared__ float4 reg4[NREG2];
    int tile = blockIdx.x;
    int td = tile % NT2; int rest = tile / NT2;
    int ty = rest % NT2; rest /= NT2;
    int a = rest % NA;
    int b = rest / NA;
    float ct, st;
    if (TBL) { ct = tbl[2 * a]; st = tbl[2 * a + 1]; }
    else     { ref_trig(a, ct, st); }
    int dlohi, gcb, grb, nrows, kske, y0i, zbase, boff;
    float pxbase, pybase;
    if (!tile_geom(a, b, td, ty, ct, st, dlohi, gcb, grb, nrows, kske, y0i,
                   zbase, boff, pxbase, pybase)) return;
    process_tile32(x + boff, zpage, ct, st, dlohi, gcb, grb, nrows, kske,
                   y0i, zbase, pxbase, pybase, reg4, z);
}

// Kernel 2: tiled backprojection, 16x16 px tiles (2048 blocks -> 8/CU,
// 32 waves/CU). Per-angle z segment (32 floats, shift addressing) + 45x16
// row-base table in LDS; 1 px/thread, 45-angle loop, 1 store.
template <int TBL>
__global__ __launch_bounds__(256) void iradon16(const float* __restrict__ z,
                                                const float* __restrict__ tbl,
                                                float* __restrict__ out) {
    __shared__ float s_sc[NA], s_st2[NA];
    __shared__ int s_lo[NA];
    __shared__ float s_B[NA * 16];
    __shared__ float s_seg[NA * SEGW2];

    int t = threadIdx.x;
    int b = blockIdx.x >> 10;
    int tb = blockIdx.x & 1023;
    int i0 = (tb >> 5) << 4;
    int j0 = (tb & 31) << 4;

    if (t < NA) {
        float ct, st;
        if (TBL) { ct = tbl[2 * t]; st = tbl[2 * t + 1]; }
        else     { ref_trig(t, ct, st); }
        float sc = ct * HALFF;
        float st2 = -st * HALFF;
        float cxl = cidx(j0 + PB), cxh = cidx(j0 + 15 + PB);
        float cyl = cidx(i0 + PB), cyh = cidx(i0 + 15 + PB);
        float a00 = fmaf(sc, cxl, fmaf(st2, cyl, 363.0f));
        float a01 = fmaf(sc, cxl, fmaf(st2, cyh, 363.0f));
        float a10 = fmaf(sc, cxh, fmaf(st2, cyl, 363.0f));
        float a11 = fmaf(sc, cxh, fmaf(st2, cyh, 363.0f));
        float mn = fminf(fminf(a00, a01), fminf(a10, a11));
        int lo = (int)floorf(mn) - 1;
        lo = min(max(lo, 0), ZSTR - 1 - SEGW2);  // keep lo..lo+31 in-row
        s_sc[t] = sc; s_st2[t] = st2; s_lo[t] = lo;
    }
    __syncthreads();

    // Row-base table: B[a][ii] = st2*cy(i0+ii) + (363 - lo)
    for (int s = t; s < NA * 16; s += 256) {
        int a = s >> 4, ii = s & 15;
        s_B[s] = fmaf(s_st2[a], cidx(i0 + ii + PB), 363.0f - (float)s_lo[a]);
    }
    // Stage z segments (L2 -> LDS, runs of 32)
    const float* zb = z + b * NA * ZSTR;
    for (int s = t; s < NA * SEGW2; s += 256) {
        int a = s >> 5, idx = s & 31;
        s_seg[s] = zb[a * ZSTR + s_lo[a] + idx];
    }
    __syncthreads();

    float cxv = cidx(j0 + (t & 15) + PB);
    int r0 = t >> 4;                              // 0..15
    float acc = 0.f;
    for (int a = 0; a < NA; ++a) {
        float af = fmaf(s_sc[a], cxv, s_B[(a << 4) + r0]);
        float fl = floorf(af);
        float wt = af - fl;
        int ia = min(max((int)af, 0), SEGW2 - 2);
        float v0 = s_seg[(a << 5) + ia], v1 = s_seg[(a << 5) + ia + 1];
        acc = fmaf(wt, v1 - v0, acc + v0);
    }
    const float sfin = (float)(PI_D / (2.0 * NA));
    out[(b << 18) + ((i0 + r0) << 9) + j0 + (t & 15)] = acc * sfin;
}

extern "C" void kernel_launch(void* const* d_in, const int* in_sizes, int n_in,
                              void* d_out, int out_size, void* d_ws, size_t ws_size,
                              hipStream_t stream) {
    const float* x = (const float*)d_in[0];     // (2,1,512,512)
    const float* yin = (const float*)d_in[1];   // (2,1,725,45)
    float* out = (float*)d_out;                 // (2,1,512,512)
    float* z = (float*)d_ws;                    // guard-padded (2,45,728)
    float* tbl = z + TBLOFF;
    int* desc = (int*)(z + DESCOFF);
    unsigned* bmap = (unsigned*)(z + BMOFF);
    float* zpage = out;                         // 256 zeros; iradon overwrites

    if (ws_size >= (size_t)WS_NEED) {
        prep<2><<<NZB + NSB, 256, 0, stream>>>(yin, z, tbl, zpage, desc, bmap);
        radon32f<<<NTILES2, 64, 0, stream>>>(x, zpage, desc, bmap, z);
        iradon16<1><<<2048, 256, 0, stream>>>(z, tbl, out);
    } else if (ws_size >= (size_t)WS_TBL) {
        prep<1><<<NZB, 256, 0, stream>>>(yin, z, tbl, zpage, nullptr, nullptr);
        radon32<1><<<NTILES2, 64, 0, stream>>>(x, zpage, tbl, z);
        iradon16<1><<<2048, 256, 0, stream>>>(z, tbl, out);
    } else {
        prep<0><<<NZB, 256, 0, stream>>>(yin, z, nullptr, zpage, nullptr, nullptr);
        radon32<0><<<NTILES2, 64, 0, stream>>>(x, zpage, nullptr, z);
        iradon16<0><<<2048, 256, 0, stream>>>(z, nullptr, out);
    }
}